// Round 1
// baseline (117.735 us; speedup 1.0000x reference)
//
#include <hip/hip_runtime.h>

// 3-level db4 DWT (zero-padding mode) as composite FIRs applied directly to x.
// child(t) = sum_j DEC[j]*parent(2t+1-j), zero-extended; composition exact.
// R11: role-split dispatch. Blocks 0..1031: compute role (R10 structure, x2
// coarsening) storing ONLY nonzero coeff rows (27.4 MB): c0/c3/c5 s<518,
// c2 s<1029, c1/c4 s<2051. Blocks 1032..2047: memset-grade zero-streamers
// covering the exact complement (73.3 MB) with contiguous f4 stores, fill-
// kernel style. Hypothesis: the 73% zero-store tail was dragging at the fat
// kernel's pace; as a pure stream it should run at ~6.5 TB/s and overlap the
// compute blocks' latency phases.

typedef float float4n __attribute__((ext_vector_type(4)));

struct Weights {
    float w1h[8];    // level-1 high:  x[2s+1-j]
    float w2h[22];   // level-2 high:  x[4s+3-m], m=2j+k
    float w3h[50];   // level-3 high:  x[8s+7-m], m=4j+2k+l
    float w3l[50];   // level-3 low (approx)
};

constexpr Weights make_weights() {
    constexpr double LO[8] = {
        -0.010597401784997278,  0.032883011666982945,  0.030841381835986965,
        -0.18703481171888114,  -0.02798376941698385,   0.6308807679295904,
         0.7148465705525415,    0.23037781330885523};
    constexpr double HI[8] = {
        -0.23037781330885523,   0.7148465705525415,   -0.6308807679295904,
        -0.02798376941698385,   0.18703481171888114,   0.030841381835986965,
         0.032883011666982945, -0.010597401784997278};
    double a2h[22] = {}, a3h[50] = {}, a3l[50] = {};
    for (int j = 0; j < 8; ++j)
        for (int k = 0; k < 8; ++k)
            a2h[2 * j + k] += HI[j] * LO[k];
    for (int j = 0; j < 8; ++j)
        for (int k = 0; k < 8; ++k)
            for (int l = 0; l < 8; ++l) {
                a3h[4 * j + 2 * k + l] += HI[j] * LO[k] * LO[l];
                a3l[4 * j + 2 * k + l] += LO[j] * LO[k] * LO[l];
            }
    Weights W = {};
    for (int i = 0; i < 8; ++i)  W.w1h[i] = (float)HI[i];
    for (int i = 0; i < 22; ++i) W.w2h[i] = (float)a2h[i];
    for (int i = 0; i < 50; ++i) { W.w3h[i] = (float)a3h[i]; W.w3l[i] = (float)a3l[i]; }
    return W;
}

__device__ __constant__ Weights CW = make_weights();

__device__ __forceinline__ void fma4(float4n& a, float c, const float4n& v) {
    a.x = fmaf(c, v.x, a.x);
    a.y = fmaf(c, v.y, a.y);
    a.z = fmaf(c, v.z, a.z);
    a.w = fmaf(c, v.w, a.w);
}

// Output geometry (units of float4): per-(chan,b) slice = 4096*32 = 131072.
// Nonzero coeff lengths: L1/d1 = 2051, L2/d2 = 1029, L3/approx/d3 = 518.
// Zero complement, per (chan,b) segment:
//   class A: chans {0,3,5}, rows [518,4096)  -> 114496 f4/seg, 24 segs = 2747904
//   class B: chan  {2},     rows [1029,4096) ->  98144 f4/seg,  8 segs =  785152
//   class C: chans {1,4},   rows [2051,4096) ->  65440 f4/seg, 16 segs = 1047040
// Zero blocks: 610 (A) + 174 (B) + 232 (C) = 1016; 18 grid-stride f4/thread.

__global__ void __launch_bounds__(256) wavelet_fused_kernel(
        const float4n* __restrict__ x, float4n* __restrict__ out) {
    int id = blockIdx.x;
    const float4n z = {0.f, 0.f, 0.f, 0.f};

    if (id >= 1032) {
        // ---------------- zero-streamer role ----------------
        int zb  = id - 1032;
        int tid = threadIdx.x;
        if (zb < 610) {                     // class A
#pragma unroll
            for (int k = 0; k < 18; ++k) {
                unsigned idx = (unsigned)zb * 256u + tid + (unsigned)k * (610u * 256u);
                if (idx < 2747904u) {
                    unsigned seg = idx / 114496u;            // 0..23
                    unsigned off = idx - seg * 114496u;
                    unsigned ci  = seg >> 3;                 // 0,1,2 -> chan 0,3,5
                    unsigned cb  = ((5u * ci + 1u) >> 1) * 8u + (seg & 7u);
                    out[(long)cb * 131072 + 518 * 32 + off] = z;
                }
            }
        } else if (zb < 784) {              // class B
            int zb2 = zb - 610;
#pragma unroll
            for (int k = 0; k < 18; ++k) {
                unsigned idx = (unsigned)zb2 * 256u + tid + (unsigned)k * (174u * 256u);
                if (idx < 785152u) {
                    unsigned seg = idx / 98144u;             // b = 0..7
                    unsigned off = idx - seg * 98144u;
                    unsigned cb  = 16u + seg;                // chan 2
                    out[(long)cb * 131072 + 1029 * 32 + off] = z;
                }
            }
        } else {                            // class C
            int zb2 = zb - 784;
#pragma unroll
            for (int k = 0; k < 18; ++k) {
                unsigned idx = (unsigned)zb2 * 256u + tid + (unsigned)k * (232u * 256u);
                if (idx < 1047040u) {
                    unsigned seg = idx / 65440u;             // 0..15
                    unsigned off = idx - seg * 65440u;
                    unsigned ci  = seg >> 3;                 // 0,1 -> chan 1,4
                    unsigned cb  = (1u + 3u * ci) * 8u + (seg & 7u);
                    out[(long)cb * 131072 + 2051 * 32 + off] = z;
                }
            }
        }
        return;
    }

    // ---------------- compute role (ids 0..1031) ----------------
    // b = id&7 (one b-slice per XCD, ~2.1 MB in its L2), c = id>>3 in [0,129).
    // Group g = tid>>5 owns q = c*8+g in [0,1032); thread owns output rows
    // s = 2q..2q+1 at f4 column f. Heavy L3 blocks remain ids 0..255.
    int b  = id & 7;
    int c  = id >> 3;
    int q  = c * 8 + (threadIdx.x >> 5);
    int f  = threadIdx.x & 31;

    const float4n* xb = x + (long)b * 4096 * 32 + f;
    float4n h1[2] = {z, z}, h2[2] = {z, z}, h3[2] = {z, z}, l3[2] = {z, z};

    // Level-3 (50-tap h+l, stride 8): rows [16q-42, 16q+15], 58 loads / 2 outputs
    if (q <= 258) {
        int rbase = 16 * q - 42;
#pragma unroll
        for (int rr = 0; rr < 58; ++rr) {
            int r = rbase + rr;
            float4n v = ((unsigned)r < 4096u) ? xb[r * 32] : z;
#pragma unroll
            for (int i = 0; i < 2; ++i) {
                int m = 8 * i + 49 - rr;           // compile-time per (rr,i)
                if (m >= 0 && m < 50) { fma4(h3[i], CW.w3h[m], v); fma4(l3[i], CW.w3l[m], v); }
            }
        }
    }
    // Level-2 (22-tap, stride 4): rows [8q-18, 8q+7], 26 loads / 2 outputs
    if (q <= 514) {
        int rbase = 8 * q - 18;
#pragma unroll
        for (int rr = 0; rr < 26; ++rr) {
            int r = rbase + rr;
            float4n v = ((unsigned)r < 4096u) ? xb[r * 32] : z;
#pragma unroll
            for (int i = 0; i < 2; ++i) {
                int m = 4 * i + 21 - rr;
                if (m >= 0 && m < 22) fma4(h2[i], CW.w2h[m], v);
            }
        }
    }
    // Level-1 (8-tap, stride 2): rows [4q-6, 4q+3], 10 loads / 2 outputs
    if (q <= 1025) {
        int rbase = 4 * q - 6;
#pragma unroll
        for (int rr = 0; rr < 10; ++rr) {
            int r = rbase + rr;
            float4n v = ((unsigned)r < 4096u) ? xb[r * 32] : z;
#pragma unroll
            for (int i = 0; i < 2; ++i) {
                int m = 2 * i + 7 - rr;
                if (m >= 0 && m < 8) fma4(h1[i], CW.w1h[m], v);
            }
        }
    }

    const long CH = 8L * 4096 * 32;
#pragma unroll
    for (int i = 0; i < 2; ++i) {
        int s = 2 * q + i;
        if (s >= 2051) continue;               // zero region: streamer covers it
        if (s >= 518)  { h3[i] = z; l3[i] = z; }   // exact zeros feeding hs
        if (s >= 1029) h2[i] = z;
        float4n hs = h1[i] + h2[i] + h3[i];
        long base = ((long)b * 4096 + s) * 32 + f;
        out[CH + base]     = h1[i];            // c1 d1        (s < 2051)
        out[4 * CH + base] = hs;               // c4 high_freq (s < 2051)
        if (s < 1029) out[2 * CH + base] = h2[i];   // c2 d2
        if (s < 518) {
            out[base]          = l3[i];        // c0 approx
            out[3 * CH + base] = h3[i];        // c3 d3
            out[5 * CH + base] = l3[i];        // c5 low_freq
        }
    }
}

extern "C" void kernel_launch(void* const* d_in, const int* in_sizes, int n_in,
                              void* d_out, int out_size, void* d_ws, size_t ws_size,
                              hipStream_t stream) {
    const float4n* x   = (const float4n*)d_in[0];   // [8, 4096, 128] f32
    float4n*       out = (float4n*)d_out;           // [6, 8, 4096, 128] f32
    wavelet_fused_kernel<<<2048, 256, 0, stream>>>(x, out);
}